// Round 4
// baseline (239.872 us; speedup 1.0000x reference)
//
#include <hip/hip_runtime.h>
#include <math.h>

#define A_N    1000
#define LQ_N   2048
#define C_N    3
#define H_N    10
#define HID_N  10000   // A_N * H_N
#define MID_N  5000
#define NPOS_N 1001
#define NOUT_N 2001
#define W2COLS 6001    // MID_N + NPOS_N

#define NBLK   1024
#define NWAVE  (NBLK * 4)        // 4096 waves
#define NTASKA 20000             // 5000 rows x 4 quarter-rows
#define QF4    625               // float4 per quarter-row
#define ROWF4  2500              // float4 per w1 row

// ws layout in floats (all 16B-aligned)
#define WS_CONC    0             // 10000 floats
#define WS_VCAT    10000         // 6004 floats [lin | pos | pad]
#define WS_PARTIAL 16016         // 20000 floats (quarter-row partials)
#define WS_BARRIER 36016         // barrier counters (u32), memset each call

__device__ __forceinline__ float sigmoidf_(float x) { return 1.0f / (1.0f + expf(-x)); }
__device__ __forceinline__ float dot4(float4 a, float4 b) {
    return a.x * b.x + a.y * b.y + a.z * b.z + a.w * b.w;
}
__device__ __forceinline__ float wave_reduce(float acc) {
    #pragma unroll
    for (int off = 32; off > 0; off >>= 1) acc += __shfl_down(acc, off, 64);
    return acc;
}

// hierarchical grid barrier: 16 sub-counters + 1 master per phase (32 u32 stride)
__device__ __forceinline__ void grid_barrier(unsigned* bar, int phase) {
    unsigned* sub    = bar + phase * 32;
    unsigned* master = sub + 16;
    __syncthreads();
    if (threadIdx.x == 0) {
        __threadfence();   // release: make this block's stores visible device-wide
        unsigned old = __hip_atomic_fetch_add(&sub[blockIdx.x & 15], 1u,
                                              __ATOMIC_ACQ_REL, __HIP_MEMORY_SCOPE_AGENT);
        if (old == (NBLK / 16) - 1)
            __hip_atomic_fetch_add(master, 1u, __ATOMIC_ACQ_REL, __HIP_MEMORY_SCOPE_AGENT);
        while (__hip_atomic_load(master, __ATOMIC_ACQUIRE, __HIP_MEMORY_SCOPE_AGENT) < 16u)
            __builtin_amdgcn_s_sleep(2);
        __threadfence();   // acquire: discard stale cached lines
    }
    __syncthreads();
}

// Kernel A: blocks 0-3: lstm head -> conc ; block 4: pos -> vcat[5000:], pad zeros
__global__ void __launch_bounds__(256) lstm_head(
    const float* __restrict__ quotes,
    const float* __restrict__ wih0, const float* __restrict__ bih0, const float* __restrict__ bhh0,
    const float* __restrict__ wih1, const float* __restrict__ bih1, const float* __restrict__ bhh1,
    const float* __restrict__ wih2, const float* __restrict__ bih2, const float* __restrict__ bhh2,
    const float* __restrict__ pos,
    float* __restrict__ conc, float* __restrict__ vcat)
{
    if (blockIdx.x == 4) {
        for (int j = threadIdx.x; j < NPOS_N; j += 256)
            vcat[MID_N + j] = pos[j];
        if (threadIdx.x < 3) vcat[W2COLS + threadIdx.x] = 0.0f;
        return;
    }

    int a = blockIdx.x * blockDim.x + threadIdx.x;
    if (a >= A_N) return;

    const float* q = quotes + (size_t)a * LQ_N * C_N + (size_t)(LQ_N - 1) * C_N;
    float x0 = q[0], x1 = q[1], x2 = q[2];

    float g[40];
    float h[H_N];

    #pragma unroll
    for (int j = 0; j < 40; ++j)
        g[j] = x0 * wih0[j * 3 + 0] + x1 * wih0[j * 3 + 1] + x2 * wih0[j * 3 + 2]
             + bih0[j] + bhh0[j];
    #pragma unroll
    for (int k = 0; k < H_N; ++k) {
        float cc = sigmoidf_(g[k]) * tanhf(g[20 + k]);
        h[k] = sigmoidf_(g[30 + k]) * tanhf(cc);
    }

    #pragma unroll
    for (int j = 0; j < 40; ++j) {
        float s = bih1[j] + bhh1[j];
        #pragma unroll
        for (int k = 0; k < H_N; ++k) s += h[k] * wih1[j * 10 + k];
        g[j] = s;
    }
    float h2[H_N];
    #pragma unroll
    for (int k = 0; k < H_N; ++k) {
        float cc = sigmoidf_(g[k]) * tanhf(g[20 + k]);
        h2[k] = sigmoidf_(g[30 + k]) * tanhf(cc);
    }

    #pragma unroll
    for (int j = 0; j < 40; ++j) {
        float s = bih2[j] + bhh2[j];
        #pragma unroll
        for (int k = 0; k < H_N; ++k) s += h2[k] * wih2[j * 10 + k];
        g[j] = s;
    }
    #pragma unroll
    for (int k = 0; k < H_N; ++k) {
        float cc = sigmoidf_(g[k]) * tanhf(g[20 + k]);
        float hh = sigmoidf_(g[30 + k]) * tanhf(cc);
        conc[a * H_N + k] = tanhf(hh);
    }
}

// Kernel B (persistent, 1024 blocks exactly resident):
//   phase A: w1 quarter-row partial dots (20000 tasks over 4096 waves)
//   barrier
//   phase B: combine 4 partials per row + bias + tanh -> vcat[0:5000]
//   barrier
//   phase C: out[r] = w2[r,:] . vcat + b2[r]  (one full row per wave)
__global__ void __launch_bounds__(256, 4) fused_mv(
    const float* __restrict__ w1, const float* __restrict__ b1,
    const float* __restrict__ w2, const float* __restrict__ b2,
    float* __restrict__ ws, float* __restrict__ out)
{
    float* conc    = ws + WS_CONC;
    float* vcat    = ws + WS_VCAT;
    float* partial = ws + WS_PARTIAL;
    unsigned* bar  = (unsigned*)(ws + WS_BARRIER);

    const int lane = threadIdx.x & 63;
    const int wid  = threadIdx.x >> 6;
    const int gw   = blockIdx.x * 4 + wid;     // global wave id, < 4096

    // ---- phase A: w1 . conc quarter-row partials ----
    {
        const float4* w1v = reinterpret_cast<const float4*>(w1);
        const float4* cv  = reinterpret_cast<const float4*>(conc);
        for (int t = gw; t < NTASKA; t += NWAVE) {
            int row = t >> 2;
            int cb  = (t & 3) * QF4;
            int ce  = cb + QF4;
            const float4* wrow = w1v + (size_t)row * ROWF4;
            float s0 = 0.f, s1 = 0.f;
            int c = cb + lane;
            #pragma unroll 1
            for (; c + 64 < ce; c += 128) {
                float4 a0 = wrow[c];      float4 v0 = cv[c];
                float4 a1 = wrow[c + 64]; float4 v1 = cv[c + 64];
                s0 += dot4(a0, v0);
                s1 += dot4(a1, v1);
            }
            if (c < ce) s0 += dot4(wrow[c], cv[c]);
            float s = wave_reduce(s0 + s1);
            if (lane == 0) partial[t] = s;
        }
    }

    grid_barrier(bar, 0);

    // ---- phase B: combine partials -> vcat[0:5000] ----
    {
        int gtid = blockIdx.x * 256 + threadIdx.x;
        if (gtid < MID_N) {
            float4 pp = *reinterpret_cast<const float4*>(partial + 4 * gtid);
            vcat[gtid] = tanhf(pp.x + pp.y + pp.z + pp.w + b1[gtid]);
        }
    }

    grid_barrier(bar, 1);

    // ---- phase C: full w2 row per wave ----
    if (gw < NOUT_N) {
        const int row = gw;
        const float* wr = w2 + (size_t)row * W2COLS;
        const int p    = (4 - (row & 3)) & 3;
        const int n    = W2COLS - p;
        const int n4   = n >> 2;
        const int tail = n & 3;

        float acc0 = 0.f, acc1 = 0.f, acc2 = 0.f, acc3 = 0.f;
        if (lane < p) acc0 += wr[lane] * vcat[lane];

        const float4* rb = reinterpret_cast<const float4*>(wr + p);
        int i = lane;
        #pragma unroll 1
        for (; i + 192 < n4; i += 256) {
            float4 a0 = rb[i];       float4 a1 = rb[i + 64];
            float4 a2 = rb[i + 128]; float4 a3 = rb[i + 192];
            int j0 = p + 4 * i, j1 = j0 + 256, j2 = j0 + 512, j3 = j0 + 768;
            acc0 += a0.x * vcat[j0] + a0.y * vcat[j0+1] + a0.z * vcat[j0+2] + a0.w * vcat[j0+3];
            acc1 += a1.x * vcat[j1] + a1.y * vcat[j1+1] + a1.z * vcat[j1+2] + a1.w * vcat[j1+3];
            acc2 += a2.x * vcat[j2] + a2.y * vcat[j2+1] + a2.z * vcat[j2+2] + a2.w * vcat[j2+3];
            acc3 += a3.x * vcat[j3] + a3.y * vcat[j3+1] + a3.z * vcat[j3+2] + a3.w * vcat[j3+3];
        }
        #pragma unroll 1
        for (; i < n4; i += 64) {
            float4 a = rb[i];
            int j = p + 4 * i;
            acc0 += a.x * vcat[j] + a.y * vcat[j+1] + a.z * vcat[j+2] + a.w * vcat[j+3];
        }
        if (lane < tail) {
            int j = p + 4 * n4 + lane;
            acc0 += wr[j] * vcat[j];
        }

        float s = wave_reduce((acc0 + acc1) + (acc2 + acc3));
        if (lane == 0) out[row] = s + b2[row];
    }
}

extern "C" void kernel_launch(void* const* d_in, const int* in_sizes, int n_in,
                              void* d_out, int out_size, void* d_ws, size_t ws_size,
                              hipStream_t stream)
{
    const float* quotes = (const float*)d_in[0];
    const float* pos    = (const float*)d_in[1];
    const float* wih0   = (const float*)d_in[2];
    const float* bih0   = (const float*)d_in[4];
    const float* bhh0   = (const float*)d_in[5];
    const float* wih1   = (const float*)d_in[6];
    const float* bih1   = (const float*)d_in[8];
    const float* bhh1   = (const float*)d_in[9];
    const float* wih2   = (const float*)d_in[10];
    const float* bih2   = (const float*)d_in[12];
    const float* bhh2   = (const float*)d_in[13];
    const float* w1     = (const float*)d_in[14];
    const float* b1     = (const float*)d_in[15];
    const float* w2     = (const float*)d_in[16];
    const float* b2     = (const float*)d_in[17];
    float* out = (float*)d_out;

    float* ws   = (float*)d_ws;
    float* conc = ws + WS_CONC;
    float* vcat = ws + WS_VCAT;

    // reset barrier counters (64 u32 region) every call — deterministic
    hipMemsetAsync((char*)d_ws + WS_BARRIER * sizeof(float), 0, 256, stream);

    lstm_head<<<5, 256, 0, stream>>>(
        quotes, wih0, bih0, bhh0, wih1, bih1, bhh1, wih2, bih2, bhh2,
        pos, conc, vcat);

    fused_mv<<<NBLK, 256, 0, stream>>>(w1, b1, w2, b2, ws, out);
}